// Round 4
// baseline (218.711 us; speedup 1.0000x reference)
//
#include <hip/hip_runtime.h>

typedef __bf16 bf16_t;
typedef __bf16 bf16x8 __attribute__((ext_vector_type(8)));
typedef float f32x4 __attribute__((ext_vector_type(4)));

#define BM 256
#define BN 256
#define BK 32

// N_NODES=24576, F=512, M_TOT=15, degrees 1,2,3 -> segments [0,3),[3,8),[8,15)
// ws layout (bytes):
//   0        W1b   (512*512 bf16)  = 524288
//   524288   W2t   (512*512 bf16)  = 524288
//   1048576  W4t   (512*1536 bf16) = 1572864
//   2621440  Wct   (512*512 bf16)  = 524288
//   3145728  bc    (512 f32)       = 2048
//   3147776  u     (512 f32)       = 2048
//   3149824  Xb / A3 (overlapped; max = 24576*1536*2 = 75497472)

__device__ __forceinline__ void g2l16(const void* g, void* l) {
    __builtin_amdgcn_global_load_lds((__attribute__((address_space(1))) void*)(g),
                                     (__attribute__((address_space(3))) void*)(l),
                                     16, 0, 0);
}

// C[m][n] = sum_k A[m][k] * Bt[n][k]  (+ bias[n])
// mode 0: store bf16; mode 1: store f32 silu(v)
// 256x256 tile, 8 waves (2x4), per-wave 128x64. Request-BW-bound regime:
// traffic = nBlk*(BM+BN)*K*2B; 256^2 halves it vs 128^2.
// 3-stage pipeline, raw s_barrier + counted vmcnt.
__global__ __launch_bounds__(512)
void gemm_bt_kernel(const bf16_t* __restrict__ A, const bf16_t* __restrict__ Bt,
                    const float* __restrict__ bias, void* __restrict__ Cout,
                    int N, int K, int mode)
{
    __shared__ __align__(16) bf16_t lA[3][BM * BK];   // 16 KB each
    __shared__ __align__(16) bf16_t lB[3][BN * BK];   // 16 KB each

    const int tid  = threadIdx.x;
    const int lane = tid & 63;
    const int wave = tid >> 6;       // 0..7
    const int wr   = wave >> 2;      // 0..1  (row group of 128)
    const int wc   = wave & 3;       // 0..3  (col group of 64)
    const int col0 = lane & 15;
    const int kh   = lane >> 4;      // 0..3

    const int bm = blockIdx.x;
    const int bn = blockIdx.y;

    // staging: 512 threads x 16B = 8KB per g2l16 round = 128 rows of 64B
    const int rs = tid >> 2;                 // 0..127
    const int cb = (tid & 3) * 16;

    const size_t strb = (size_t)K * 2;       // row stride in bytes (both A and Bt)
    const char* gA = (const char*)A  + ((size_t)bm * BM + rs) * strb + cb;
    const char* gB = (const char*)Bt + ((size_t)bn * BN + rs) * strb + cb;

    f32x4 acc[8][4] = {};

    auto stage = [&](int kt, int buf) {
        const size_t kb = (size_t)kt * (BK * 2);
        char* la = (char*)&lA[buf][0] + tid * 16;
        char* lb = (char*)&lB[buf][0] + tid * 16;
        g2l16(gA + kb,              la);
        g2l16(gA + 128 * strb + kb, la + 8192);
        g2l16(gB + kb,              lb);
        g2l16(gB + 128 * strb + kb, lb + 8192);
    };

    auto compute = [&](int buf) {
        const bf16x8* pa = (const bf16x8*)(&lA[buf][0] + (wr * 128 + col0) * BK + kh * 8);
        const bf16x8* pb = (const bf16x8*)(&lB[buf][0] + (wc * 64  + col0) * BK + kh * 8);
        bf16x8 av[8], bw[4];
#pragma unroll
        for (int i = 0; i < 8; ++i) av[i] = pa[i * 64];   // +16 rows = 512 elems = 64 vecs
#pragma unroll
        for (int i = 0; i < 4; ++i) bw[i] = pb[i * 64];
#pragma unroll
        for (int mi = 0; mi < 8; ++mi)
#pragma unroll
            for (int ni = 0; ni < 4; ++ni)
                acc[mi][ni] = __builtin_amdgcn_mfma_f32_16x16x32_bf16(
                    av[mi], bw[ni], acc[mi][ni], 0, 0, 0);
    };

    const int nk = K / BK;       // >= 16 for all our shapes
    stage(0, 0);
    stage(1, 1);                 // 8 loads in flight; no barrier yet

    for (int kt = 0; kt < nk; ++kt) {
        if (kt + 2 < nk) {
            stage(kt + 2, (kt + 2) % 3);                      // 12 in flight
            asm volatile("s_waitcnt vmcnt(8)" ::: "memory");  // tile-kt retired
        } else if (kt + 1 < nk) {
            asm volatile("s_waitcnt vmcnt(4)" ::: "memory");
        } else {
            asm volatile("s_waitcnt vmcnt(0)" ::: "memory");
        }
        __builtin_amdgcn_s_barrier();        // all waves' tile-kt loads landed
        __builtin_amdgcn_sched_barrier(0);   // no ds_read hoisting above barrier
        __builtin_amdgcn_s_setprio(1);
        compute(kt % 3);
        __builtin_amdgcn_s_setprio(0);
        __builtin_amdgcn_sched_barrier(0);
        __builtin_amdgcn_s_barrier();        // all reads of buf kt%3 done before reuse
    }

    // C/D frag layout: col = lane&15, row = (lane>>4)*4 + j   [guide-verified]
    const int gr0 = bm * BM + wr * 128 + kh * 4;
    const int gc0 = bn * BN + wc * 64 + col0;
    if (mode == 0) {
        bf16_t* C = (bf16_t*)Cout;
#pragma unroll
        for (int mi = 0; mi < 8; ++mi)
#pragma unroll
            for (int ni = 0; ni < 4; ++ni) {
                const int c = gc0 + ni * 16;
                const float bv = bias ? bias[c] : 0.f;
#pragma unroll
                for (int j = 0; j < 4; ++j) {
                    const int r = gr0 + mi * 16 + j;
                    C[(size_t)r * N + c] = (bf16_t)(acc[mi][ni][j] + bv);
                }
            }
    } else {
        float* C = (float*)Cout;
#pragma unroll
        for (int mi = 0; mi < 8; ++mi)
#pragma unroll
            for (int ni = 0; ni < 4; ++ni) {
                const int c = gc0 + ni * 16;
                const float bv = bias[c];
#pragma unroll
                for (int j = 0; j < 4; ++j) {
                    const int r = gr0 + mi * 16 + j;
                    float v = acc[mi][ni][j] + bv;
                    C[(size_t)r * N + c] = v / (1.f + __expf(-v));
                }
            }
    }
}

__global__ void cast8_kernel(const float* __restrict__ in, bf16_t* __restrict__ out, int n8) {
    const int i = blockIdx.x * blockDim.x + threadIdx.x;
    if (i >= n8) return;
    const float4* p = (const float4*)in + (size_t)i * 2;
    float4 a = p[0], b = p[1];
    bf16x8 v;
    v[0] = (bf16_t)a.x; v[1] = (bf16_t)a.y; v[2] = (bf16_t)a.z; v[3] = (bf16_t)a.w;
    v[4] = (bf16_t)b.x; v[5] = (bf16_t)b.y; v[6] = (bf16_t)b.z; v[7] = (bf16_t)b.w;
    *(bf16x8*)(out + (size_t)i * 8) = v;
}

// out[c*R + r] = in[r*C + c]   (in: R x C, out: C x R), cast to bf16
__global__ void transpose_cast_kernel(const float* __restrict__ in, bf16_t* __restrict__ out,
                                      int R, int C) {
    const int idx = blockIdx.x * blockDim.x + threadIdx.x;
    if (idx >= R * C) return;
    const int c = idx / R;
    const int r = idx - c * R;
    out[idx] = (bf16_t)in[(size_t)r * C + c];
}

// u[t] = sum_i v[i] * W[i][t]
__global__ void vecmat_kernel(const float* __restrict__ v, const float* __restrict__ W,
                              float* __restrict__ out) {
    const int t = blockIdx.x * blockDim.x + threadIdx.x;
    if (t >= 512) return;
    float s = 0.f;
    for (int i = 0; i < 512; ++i) s += v[i] * W[i * 512 + t];
    out[t] = s;
}

// per node: s = g.W3 ; chi_bo = chi*s ; A3[n, l*512+f] = c_l * g[f]^2
__global__ __launch_bounds__(256)
void mid_kernel(const bf16_t* __restrict__ G, const float* __restrict__ chi,
                const float* __restrict__ W3, float* __restrict__ chbo,
                bf16_t* __restrict__ A3)
{
    const int node = blockIdx.x * 4 + (threadIdx.x >> 6);
    const int lane = threadIdx.x & 63;

    const bf16x8 gv = *(const bf16x8*)(G + (size_t)node * 512 + lane * 8);
    float g[8];
#pragma unroll
    for (int j = 0; j < 8; ++j) g[j] = (float)gv[j];

    float s = 0.f;
    const float* w = W3 + lane * 8;
#pragma unroll
    for (int j = 0; j < 8; ++j) s += g[j] * w[j];
#pragma unroll
    for (int off = 32; off > 0; off >>= 1) s += __shfl_xor(s, off, 64);

    const float* ch = chi + (size_t)node * 15;
    float c0 = 0.f, c1 = 0.f, c2 = 0.f;
#pragma unroll
    for (int m = 0; m < 3; ++m)  c0 += ch[m] * ch[m];
#pragma unroll
    for (int m = 3; m < 8; ++m)  c1 += ch[m] * ch[m];
#pragma unroll
    for (int m = 8; m < 15; ++m) c2 += ch[m] * ch[m];

    if (lane < 15) chbo[(size_t)node * 15 + lane] = ch[lane] * s;

    const float cl[3] = {c0, c1, c2};
    bf16_t* arow = A3 + (size_t)node * 1536 + lane * 8;
#pragma unroll
    for (int l = 0; l < 3; ++l) {
        bf16x8 o;
#pragma unroll
        for (int j = 0; j < 8; ++j) o[j] = (bf16_t)(cl[l] * g[j] * g[j]);
        *(bf16x8*)(arow + l * 512) = o;
    }
}

extern "C" void kernel_launch(void* const* d_in, const int* in_sizes, int n_in,
                              void* d_out, int out_size, void* d_ws, size_t ws_size,
                              hipStream_t stream)
{
    const float* x   = (const float*)d_in[0];
    const float* chi = (const float*)d_in[1];
    // d_in[2] = z_one_hot : unused by the reference computation
    const float* W1  = (const float*)d_in[3];
    const float* b1  = (const float*)d_in[4];
    const float* W2  = (const float*)d_in[5];
    const float* W3  = (const float*)d_in[6];
    const float* W4  = (const float*)d_in[7];
    const float* b4  = (const float*)d_in[8];

    char* ws = (char*)d_ws;
    bf16_t* W1b = (bf16_t*)(ws + 0);
    bf16_t* W2t = (bf16_t*)(ws + 524288);
    bf16_t* W4t = (bf16_t*)(ws + 1048576);
    bf16_t* Wct = (bf16_t*)(ws + 2621440);
    float*  bc  = (float*) (ws + 3145728);
    float*  u   = (float*) (ws + 3147776);
    bf16_t* Xb  = (bf16_t*)(ws + 3149824);
    bf16_t* A3  = (bf16_t*)(ws + 3149824);   // overlaps Xb (dead by then)

    float*  xbo  = (float*)d_out;                                // 24576*512 f32
    float*  chbo = (float*)d_out + (size_t)24576 * 512;          // 24576*15 f32
    bf16_t* Gb   = (bf16_t*)d_out;   // bf16 scratch inside chunk0 (dead before final GEMM)

    // prep: casts / transposes / fused bias  bc = (b1 @ W1) @ W2
    cast8_kernel<<<6144, 256, 0, stream>>>(x, Xb, 1572864);
    cast8_kernel<<<128, 256, 0, stream>>>(W1, W1b, 32768);
    transpose_cast_kernel<<<1024, 256, 0, stream>>>(W2, W2t, 512, 512);
    transpose_cast_kernel<<<3072, 256, 0, stream>>>(W4, W4t, 1536, 512);
    vecmat_kernel<<<2, 256, 0, stream>>>(b1, W1, u);
    vecmat_kernel<<<2, 256, 0, stream>>>(u, W2, bc);

    // Wct = (W1@W2)^T = W2^T @ W1^T :  C[j][i] = sum_t W2t[j][t] * W1[i][t]
    gemm_bt_kernel<<<dim3(2, 2), 512, 0, stream>>>(W2t, W1b, nullptr, Wct, 512, 512, 0);

    // G = x @ (W1@W2) + bc : C[n][j] = sum_k Xb[n][k] * Wct[j][k] + bc[j]  -> bf16
    gemm_bt_kernel<<<dim3(96, 2), 512, 0, stream>>>(Xb, Wct, bc, Gb, 512, 512, 0);

    // s, chi_bo, A3
    mid_kernel<<<6144, 256, 0, stream>>>(Gb, chi, W3, chbo, A3);

    // x_bo = silu(A3 @ W4 + b4) : C[n][j] = sum_k A3[n][k] * W4t[j][k]
    gemm_bt_kernel<<<dim3(96, 2), 512, 0, stream>>>(A3, W4t, b4, xbo, 512, 1536, 1);
}

// Round 5
// 195.741 us; speedup vs baseline: 1.1173x; 1.1173x over previous
//
#include <hip/hip_runtime.h>

typedef __bf16 bf16_t;
typedef __bf16 bf16x8 __attribute__((ext_vector_type(8)));
typedef float f32x4 __attribute__((ext_vector_type(4)));

#define BM 256
#define BN 256
#define BK 64

// ws layout (bytes):
//   0        W1b   (512*512 bf16)  = 524288
//   524288   W2t   (512*512 bf16)  = 524288
//   1048576  W4t   (512*1536 bf16) = 1572864
//   2621440  Wct   (512*512 bf16)  = 524288
//   3145728  bc    (512 f32)       = 2048
//   3147776  u     (512 f32)       = 2048
//   3149824  Xb / A3 (overlapped; max = 24576*1536*2 = 75497472)

__device__ __forceinline__ void g2l16(const void* g, void* l) {
    __builtin_amdgcn_global_load_lds((__attribute__((address_space(1))) void*)(g),
                                     (__attribute__((address_space(3))) void*)(l),
                                     16, 0, 0);
}

#define SB()  __builtin_amdgcn_sched_barrier(0)
#define BAR() __builtin_amdgcn_s_barrier()

// 8-phase-style 256x256 GEMM (m201 template, plain HIP):
// BK=64, 8 waves (2Mx4N), per-wave 128x64, 2-dbuf LDS 128KB, st_16x32 swizzle
// (byte ^= ((byte>>9)&1)<<5 within each 16KB half-tile; linear LDS dest +
// inverse-swizzled global src + swizzled read addr).
// Per K-tile: 4 phases = 4 C-quadrants x 16 MFMA, each phase also stages one
// half-tile of tile t+1 (2 x global_load_lds); vmcnt(0) only at tile boundary.
__global__ __launch_bounds__(512, 2)
void gemm_bt_kernel(const bf16_t* __restrict__ A, const bf16_t* __restrict__ Bt,
                    const float* __restrict__ bias, void* __restrict__ Cout,
                    int N, int K, int mode)
{
    __shared__ __align__(16) bf16_t lA[2][16384];   // [buf][2 halves x 8192 elems] 32KB/buf
    __shared__ __align__(16) bf16_t lB[2][16384];

    const int tid  = threadIdx.x;
    const int lane = tid & 63;
    const int wave = tid >> 6;       // 0..7
    const int wr   = wave >> 2;      // 0..1  (row group of 128)
    const int wc   = wave & 3;       // 0..3  (col group of 64)
    const int l15  = lane & 15;
    const int lh   = lane >> 4;      // 0..3

    const int bm = blockIdx.x;
    const int bn = blockIdx.y;

    const size_t strb = (size_t)K * 2;       // row stride in bytes (A and Bt)

    // ---- staging precompute (both g2l16 rounds per half-tile) ----
    // q = linear byte in 16KB half-buffer; row=q>>7, col=q&127
    // source col is inverse-swizzled so that swizzled READS see original data.
    const int q0 = tid * 16;
    const int q1 = q0 + 8192;
    const size_t ro0 = (size_t)(q0 >> 7) * strb + ((q0 ^ (((q0 >> 9) & 1) << 5)) & 127);
    const size_t ro1 = (size_t)(q1 >> 7) * strb + ((q1 ^ (((q1 >> 9) & 1) << 5)) & 127);
    const char* gA = (const char*)A  + (size_t)bm * BM * strb;
    const char* gB = (const char*)Bt + (size_t)bn * BN * strb;
    char* baseA = (char*)&lA[0][0];
    char* baseB = (char*)&lB[0][0];

#define STAGEA(T_, H_, BUF_) do{ \
    char* _d = baseA + (BUF_)*32768 + (H_)*16384; \
    const char* _s = gA + (size_t)(H_)*128*strb + (size_t)(T_)*128; \
    g2l16(_s + ro0, _d + q0); g2l16(_s + ro1, _d + q1); }while(0)
#define STAGEB(T_, H_, BUF_) do{ \
    char* _d = baseB + (BUF_)*32768 + (H_)*16384; \
    const char* _s = gB + (size_t)(H_)*128*strb + (size_t)(T_)*128; \
    g2l16(_s + ro0, _d + q0); g2l16(_s + ro1, _d + q1); }while(0)

    // ---- read-side swizzled fragment addresses ----
    // A frag (mh,m,kk): byte = wr*16384 + mh*8192 + m*2048 + kk*64 + [(l15*128+lh*16)^swz]
    // B frag (nh,n,kk): byte = (wc>>1)*16384 + nh*4096 + n*2048 + kk*64
    //                          + [(((wc&1)*64+l15)*128+lh*16)^swz]
    // swz bit5 flips with bit2 of local row == bit2 of lane (constant per lane).
    const int swz  = ((lane >> 2) & 1) << 5;
    const int aOffC = wr * 16384 + ((l15 * 128 + lh * 16) ^ swz);
    const int bOffC = (wc >> 1) * 16384 + ((((wc & 1) * 64 + l15) * 128 + lh * 16) ^ swz);

#define LOADA(AF, BUF_, MH_) do{ \
    const char* _p = baseA + (BUF_)*32768 + aOffC + (MH_)*8192; \
    _Pragma("unroll") for (int m = 0; m < 4; ++m) \
    _Pragma("unroll") for (int kk = 0; kk < 2; ++kk) \
        AF[m][kk] = *(const bf16x8*)(_p + m*2048 + kk*64); }while(0)
#define LOADB(BF, BUF_, NH_) do{ \
    const char* _p = baseB + (BUF_)*32768 + bOffC + (NH_)*4096; \
    _Pragma("unroll") for (int n = 0; n < 2; ++n) \
    _Pragma("unroll") for (int kk = 0; kk < 2; ++kk) \
        BF[n][kk] = *(const bf16x8*)(_p + n*2048 + kk*64); }while(0)

    f32x4 acc[2][2][4][2] = {};

#define MMAQ(MH_, NH_, AF, BF) do{ \
    __builtin_amdgcn_s_setprio(1); \
    _Pragma("unroll") for (int m = 0; m < 4; ++m) \
    _Pragma("unroll") for (int n = 0; n < 2; ++n) \
    _Pragma("unroll") for (int kk = 0; kk < 2; ++kk) \
        acc[MH_][NH_][m][n] = __builtin_amdgcn_mfma_f32_16x16x32_bf16( \
            AF[m][kk], BF[n][kk], acc[MH_][NH_][m][n], 0, 0, 0); \
    __builtin_amdgcn_s_setprio(0); }while(0)

    const int T = K / BK;

    // prologue: stage tile 0 fully, drain, sync
    STAGEA(0, 0, 0); STAGEA(0, 1, 0); STAGEB(0, 0, 0); STAGEB(0, 1, 0);
    asm volatile("s_waitcnt vmcnt(0)" ::: "memory");
    BAR();

    for (int t = 0; t < T; ++t) {
        const int buf = t & 1, nbuf = buf ^ 1;
        const bool pf = (t + 1 < T);
        bf16x8 a0[4][2], a1[4][2], b0[2][2], b1[2][2];

        // ---- phase 1: quadrant (0,0)
        LOADA(a0, buf, 0); LOADB(b0, buf, 0);
        if (pf) STAGEA(t + 1, 0, nbuf);
        SB(); BAR();
        MMAQ(0, 0, a0, b0);
        SB(); BAR();

        // ---- phase 2: quadrant (0,1)
        LOADB(b1, buf, 1);
        if (pf) STAGEA(t + 1, 1, nbuf);
        SB(); BAR();
        MMAQ(0, 1, a0, b1);
        SB(); BAR();

        // ---- phase 3: quadrant (1,0)
        LOADA(a1, buf, 1);
        if (pf) STAGEB(t + 1, 0, nbuf);
        SB(); BAR();
        MMAQ(1, 0, a1, b0);
        SB(); BAR();

        // ---- phase 4: quadrant (1,1) + tile-boundary drain
        if (pf) STAGEB(t + 1, 1, nbuf);
        SB(); BAR();
        MMAQ(1, 1, a1, b1);
        SB();
        asm volatile("s_waitcnt vmcnt(0)" ::: "memory");  // t+1 loads aged >=3 phases
        BAR();
    }

    // C/D frag layout: col = lane&15, row = (lane>>4)*4 + j
    const int gr0 = bm * BM + wr * 128 + lh * 4;
    const int gc0 = bn * BN + wc * 64 + l15;
    if (mode == 0) {
        bf16_t* C = (bf16_t*)Cout;
#pragma unroll
        for (int mh = 0; mh < 2; ++mh)
#pragma unroll
        for (int nh = 0; nh < 2; ++nh)
#pragma unroll
        for (int m = 0; m < 4; ++m)
#pragma unroll
        for (int n = 0; n < 2; ++n) {
            const int c = gc0 + nh * 32 + n * 16;
            const float bv = bias ? bias[c] : 0.f;
#pragma unroll
            for (int j = 0; j < 4; ++j) {
                const int r = gr0 + mh * 64 + m * 16 + j;
                C[(size_t)r * N + c] = (bf16_t)(acc[mh][nh][m][n][j] + bv);
            }
        }
    } else {
        float* C = (float*)Cout;
#pragma unroll
        for (int mh = 0; mh < 2; ++mh)
#pragma unroll
        for (int nh = 0; nh < 2; ++nh)
#pragma unroll
        for (int m = 0; m < 4; ++m)
#pragma unroll
        for (int n = 0; n < 2; ++n) {
            const int c = gc0 + nh * 32 + n * 16;
            const float bv = bias[c];
#pragma unroll
            for (int j = 0; j < 4; ++j) {
                const int r = gr0 + mh * 64 + m * 16 + j;
                float v = acc[mh][nh][m][n][j] + bv;
                C[(size_t)r * N + c] = v / (1.f + __expf(-v));
            }
        }
    }
#undef STAGEA
#undef STAGEB
#undef LOADA
#undef LOADB
#undef MMAQ
}

__global__ void cast8_kernel(const float* __restrict__ in, bf16_t* __restrict__ out, int n8) {
    const int i = blockIdx.x * blockDim.x + threadIdx.x;
    if (i >= n8) return;
    const float4* p = (const float4*)in + (size_t)i * 2;
    float4 a = p[0], b = p[1];
    bf16x8 v;
    v[0] = (bf16_t)a.x; v[1] = (bf16_t)a.y; v[2] = (bf16_t)a.z; v[3] = (bf16_t)a.w;
    v[4] = (bf16_t)b.x; v[5] = (bf16_t)b.y; v[6] = (bf16_t)b.z; v[7] = (bf16_t)b.w;
    *(bf16x8*)(out + (size_t)i * 8) = v;
}

// out[c*R + r] = in[r*C + c]   (in: R x C, out: C x R), cast to bf16
__global__ void transpose_cast_kernel(const float* __restrict__ in, bf16_t* __restrict__ out,
                                      int R, int C) {
    const int idx = blockIdx.x * blockDim.x + threadIdx.x;
    if (idx >= R * C) return;
    const int c = idx / R;
    const int r = idx - c * R;
    out[idx] = (bf16_t)in[(size_t)r * C + c];
}

// u[t] = sum_i v[i] * W[i][t]
__global__ void vecmat_kernel(const float* __restrict__ v, const float* __restrict__ W,
                              float* __restrict__ out) {
    const int t = blockIdx.x * blockDim.x + threadIdx.x;
    if (t >= 512) return;
    float s = 0.f;
    for (int i = 0; i < 512; ++i) s += v[i] * W[i * 512 + t];
    out[t] = s;
}

// per node: s = g.W3 ; chi_bo = chi*s ; A3[n, l*512+f] = c_l * g[f]^2
__global__ __launch_bounds__(256)
void mid_kernel(const bf16_t* __restrict__ G, const float* __restrict__ chi,
                const float* __restrict__ W3, float* __restrict__ chbo,
                bf16_t* __restrict__ A3)
{
    const int node = blockIdx.x * 4 + (threadIdx.x >> 6);
    const int lane = threadIdx.x & 63;

    const bf16x8 gv = *(const bf16x8*)(G + (size_t)node * 512 + lane * 8);
    float g[8];
#pragma unroll
    for (int j = 0; j < 8; ++j) g[j] = (float)gv[j];

    float s = 0.f;
    const float* w = W3 + lane * 8;
#pragma unroll
    for (int j = 0; j < 8; ++j) s += g[j] * w[j];
#pragma unroll
    for (int off = 32; off > 0; off >>= 1) s += __shfl_xor(s, off, 64);

    const float* ch = chi + (size_t)node * 15;
    float c0 = 0.f, c1 = 0.f, c2 = 0.f;
#pragma unroll
    for (int m = 0; m < 3; ++m)  c0 += ch[m] * ch[m];
#pragma unroll
    for (int m = 3; m < 8; ++m)  c1 += ch[m] * ch[m];
#pragma unroll
    for (int m = 8; m < 15; ++m) c2 += ch[m] * ch[m];

    if (lane < 15) chbo[(size_t)node * 15 + lane] = ch[lane] * s;

    const float cl[3] = {c0, c1, c2};
    bf16_t* arow = A3 + (size_t)node * 1536 + lane * 8;
#pragma unroll
    for (int l = 0; l < 3; ++l) {
        bf16x8 o;
#pragma unroll
        for (int j = 0; j < 8; ++j) o[j] = (bf16_t)(cl[l] * g[j] * g[j]);
        *(bf16x8*)(arow + l * 512) = o;
    }
}

extern "C" void kernel_launch(void* const* d_in, const int* in_sizes, int n_in,
                              void* d_out, int out_size, void* d_ws, size_t ws_size,
                              hipStream_t stream)
{
    const float* x   = (const float*)d_in[0];
    const float* chi = (const float*)d_in[1];
    // d_in[2] = z_one_hot : unused by the reference computation
    const float* W1  = (const float*)d_in[3];
    const float* b1  = (const float*)d_in[4];
    const float* W2  = (const float*)d_in[5];
    const float* W3  = (const float*)d_in[6];
    const float* W4  = (const float*)d_in[7];
    const float* b4  = (const float*)d_in[8];

    char* ws = (char*)d_ws;
    bf16_t* W1b = (bf16_t*)(ws + 0);
    bf16_t* W2t = (bf16_t*)(ws + 524288);
    bf16_t* W4t = (bf16_t*)(ws + 1048576);
    bf16_t* Wct = (bf16_t*)(ws + 2621440);
    float*  bc  = (float*) (ws + 3145728);
    float*  u   = (float*) (ws + 3147776);
    bf16_t* Xb  = (bf16_t*)(ws + 3149824);
    bf16_t* A3  = (bf16_t*)(ws + 3149824);   // overlaps Xb (dead by then)

    float*  xbo  = (float*)d_out;                                // 24576*512 f32
    float*  chbo = (float*)d_out + (size_t)24576 * 512;          // 24576*15 f32
    bf16_t* Gb   = (bf16_t*)d_out;   // bf16 scratch inside chunk0 (dead before final GEMM)

    // prep: casts / transposes / fused bias  bc = (b1 @ W1) @ W2
    cast8_kernel<<<6144, 256, 0, stream>>>(x, Xb, 1572864);
    cast8_kernel<<<128, 256, 0, stream>>>(W1, W1b, 32768);
    transpose_cast_kernel<<<1024, 256, 0, stream>>>(W2, W2t, 512, 512);
    transpose_cast_kernel<<<3072, 256, 0, stream>>>(W4, W4t, 1536, 512);
    vecmat_kernel<<<2, 256, 0, stream>>>(b1, W1, u);
    vecmat_kernel<<<2, 256, 0, stream>>>(u, W2, bc);

    // Wct = (W1@W2)^T = W2^T @ W1^T :  C[j][i] = sum_t W2t[j][t] * W1[i][t]
    gemm_bt_kernel<<<dim3(2, 2), 512, 0, stream>>>(W2t, W1b, nullptr, Wct, 512, 512, 0);

    // G = x @ (W1@W2) + bc : C[n][j] = sum_k Xb[n][k] * Wct[j][k] + bc[j]  -> bf16
    gemm_bt_kernel<<<dim3(96, 2), 512, 0, stream>>>(Xb, Wct, bc, Gb, 512, 512, 0);

    // s, chi_bo, A3
    mid_kernel<<<6144, 256, 0, stream>>>(Gb, chi, W3, chbo, A3);

    // x_bo = silu(A3 @ W4 + b4) : C[n][j] = sum_k A3[n][k] * W4t[j][k]
    gemm_bt_kernel<<<dim3(96, 2), 512, 0, stream>>>(A3, W4t, b4, xbo, 512, 1536, 1);
}

// Round 6
// 180.138 us; speedup vs baseline: 1.2141x; 1.0866x over previous
//
#include <hip/hip_runtime.h>

typedef __bf16 bf16_t;
typedef __bf16 bf16x8 __attribute__((ext_vector_type(8)));
typedef float f32x4 __attribute__((ext_vector_type(4)));

#define BN 256
#define BK 64

// ws layout (bytes):
//   0        W1b   (512*512 bf16)  = 524288
//   524288   W2t   (512*512 bf16)  = 524288
//   1048576  W4t   (512*1536 bf16) = 1572864
//   2621440  Wct   (512*512 bf16)  = 524288
//   3145728  bc    (512 f32)       = 2048
//   3147776  u     (512 f32)       = 2048
//   3149824  Xb / A3 (overlapped; max = 24576*1536*2 = 75497472)

__device__ __forceinline__ void g2l16(const void* g, void* l) {
    __builtin_amdgcn_global_load_lds((__attribute__((address_space(1))) void*)(g),
                                     (__attribute__((address_space(3))) void*)(l),
                                     16, 0, 0);
}

#define SB()  __builtin_amdgcn_sched_barrier(0)
#define BAR() __builtin_amdgcn_s_barrier()

// 4-phase double-buffered 8-wave GEMM, tile (32*MF) x 256, BK=64.
// MF = m-frags per wave (wave tile = MF*16 rows x 64 cols).
//   MF=6 -> BM=192: grid for M=24576,N=512 is (128,2)=256 blocks = 1/CU exact.
//   MF=8 -> BM=256: used for the small 512x512 weight GEMM.
// LDS swizzle: byte ^= ((row&7)<<4) (both-sides involution: inverse-swizzled
// global source + swizzled ds_read; spreads column-slice b128 reads over all
// 32 banks — bank-group = (kk*4+lh) ^ (l15&7) covers 0..7 evenly).
template<int MF>
__global__ __launch_bounds__(512)
void gemm_bt_kernel(const bf16_t* __restrict__ A, const bf16_t* __restrict__ Bt,
                    const float* __restrict__ bias, void* __restrict__ Cout,
                    int N, int K, int mode)
{
    constexpr int MF2    = MF / 2;
    constexpr int ABYTES = MF * 4096;          // bytes per A buffer (MF*32 rows x 128B)
    constexpr int RA     = MF * 32 / 64;       // A staging rounds (8KB each): 3 or 4

    __shared__ __align__(16) bf16_t lA[2][MF * 2048];
    __shared__ __align__(16) bf16_t lB[2][16384];

    const int tid  = threadIdx.x;
    const int lane = tid & 63;
    const int wave = tid >> 6;       // 0..7
    const int wr   = wave >> 2;      // 0..1
    const int wc   = wave & 3;       // 0..3
    const int l15  = lane & 15;
    const int lh   = lane >> 4;      // 0..3

    const int bm = blockIdx.x;
    const int bn = blockIdx.y;

    const size_t strb = (size_t)K * 2;

    // ---- staging: one g2l16 = 8KB round (64 rows x 128B), 512 thr x 16B ----
    const int q0 = tid * 16;                       // linear byte in round
    // inverse-swizzled source column: col ^ ((row&7)<<4), row = q0>>7
    const size_t rowOff = (size_t)(q0 >> 7) * strb + ((q0 ^ (((q0 >> 7) & 7) << 4)) & 127);
    const char* gA = (const char*)A  + (size_t)bm * (MF * 32) * strb + rowOff;
    const char* gB = (const char*)Bt + (size_t)bn * BN * strb + rowOff;
    char* baseA = (char*)&lA[0][0];
    char* baseB = (char*)&lB[0][0];

    auto stageA = [&](int t, int buf, int r) {
        g2l16(gA + (size_t)t * 128 + (size_t)(r * 64) * strb,
              baseA + buf * ABYTES + r * 8192 + q0);
    };
    auto stageB = [&](int t, int buf, int r) {
        g2l16(gB + (size_t)t * 128 + (size_t)(r * 64) * strb,
              baseB + buf * 32768 + r * 8192 + q0);
    };

    // ---- swizzled read addresses ----
    const int swzr = (l15 & 7) << 4;
    const int xk0  = (lh * 16) ^ swzr;            // kk=0 column byte
    const int xk1  = (64 + lh * 16) ^ swzr;       // kk=1
    const int aOff = wr * (MF2 * 2) * 2048 + l15 * 128;   // wave row base + lane row
    const int bOff = wc * 8192 + l15 * 128;

    f32x4 acc[2][2][MF2][2] = {};

#define LOADA(AF, BUF_, MH_) do{ \
    const char* _p = baseA + (BUF_)*ABYTES + aOff + (MH_)*(MF2*2048); \
    _Pragma("unroll") for (int m = 0; m < MF2; ++m) { \
        AF[m][0] = *(const bf16x8*)(_p + m*2048 + xk0); \
        AF[m][1] = *(const bf16x8*)(_p + m*2048 + xk1); } }while(0)
#define LOADB(BF, BUF_, NH_) do{ \
    const char* _p = baseB + (BUF_)*32768 + bOff + (NH_)*4096; \
    _Pragma("unroll") for (int n = 0; n < 2; ++n) { \
        BF[n][0] = *(const bf16x8*)(_p + n*2048 + xk0); \
        BF[n][1] = *(const bf16x8*)(_p + n*2048 + xk1); } }while(0)
#define MMAQ(MH_, NH_, AF, BF) do{ \
    __builtin_amdgcn_s_setprio(1); \
    _Pragma("unroll") for (int m = 0; m < MF2; ++m) \
    _Pragma("unroll") for (int n = 0; n < 2; ++n) \
    _Pragma("unroll") for (int kk = 0; kk < 2; ++kk) \
        acc[MH_][NH_][m][n] = __builtin_amdgcn_mfma_f32_16x16x32_bf16( \
            AF[m][kk], BF[n][kk], acc[MH_][NH_][m][n], 0, 0, 0); \
    __builtin_amdgcn_s_setprio(0); }while(0)

    const int T = K / BK;

    // prologue: stage tile 0 fully
#pragma unroll
    for (int r = 0; r < RA; ++r) stageA(0, 0, r);
#pragma unroll
    for (int r = 0; r < 4; ++r)  stageB(0, 0, r);
    asm volatile("s_waitcnt vmcnt(0)" ::: "memory");
    BAR();

    for (int t = 0; t < T; ++t) {
        const int buf = t & 1, nbuf = buf ^ 1;
        const bool pf = (t + 1 < T);
        bf16x8 a0[MF2][2], a1[MF2][2], b0[2][2], b1[2][2];

        // phase 1: quadrant (0,0); stage A rounds 0-1
        LOADA(a0, buf, 0); LOADB(b0, buf, 0);
        if (pf) { stageA(t + 1, nbuf, 0); stageA(t + 1, nbuf, 1); }
        SB(); BAR();
        MMAQ(0, 0, a0, b0);
        SB(); BAR();

        // phase 2: quadrant (0,1); stage remaining A rounds
        LOADB(b1, buf, 1);
        if (pf) {
            stageA(t + 1, nbuf, 2);
            if (RA == 4) stageA(t + 1, nbuf, 3);
        }
        SB(); BAR();
        MMAQ(0, 1, a0, b1);
        SB(); BAR();

        // phase 3: quadrant (1,0); stage B rounds 0-1
        LOADA(a1, buf, 1);
        if (pf) { stageB(t + 1, nbuf, 0); stageB(t + 1, nbuf, 1); }
        SB(); BAR();
        MMAQ(1, 0, a1, b0);
        SB(); BAR();

        // phase 4: quadrant (1,1); stage B rounds 2-3; boundary drain
        if (pf) { stageB(t + 1, nbuf, 2); stageB(t + 1, nbuf, 3); }
        SB(); BAR();
        MMAQ(1, 1, a1, b1);
        SB();
        asm volatile("s_waitcnt vmcnt(0)" ::: "memory");
        BAR();
    }

    // C/D frag layout: col = lane&15, row = (lane>>4)*4 + j
    const int gr0 = bm * (MF * 32) + wr * (MF2 * 32) + lh * 4;
    const int gc0 = bn * BN + wc * 64 + l15;
    if (mode == 0) {
        bf16_t* C = (bf16_t*)Cout;
#pragma unroll
        for (int mh = 0; mh < 2; ++mh)
#pragma unroll
        for (int nh = 0; nh < 2; ++nh)
#pragma unroll
        for (int m = 0; m < MF2; ++m)
#pragma unroll
        for (int n = 0; n < 2; ++n) {
            const int c = gc0 + nh * 32 + n * 16;
            const float bv = bias ? bias[c] : 0.f;
#pragma unroll
            for (int j = 0; j < 4; ++j) {
                const int r = gr0 + (mh * MF2 + m) * 16 + j;
                C[(size_t)r * N + c] = (bf16_t)(acc[mh][nh][m][n][j] + bv);
            }
        }
    } else {
        float* C = (float*)Cout;
#pragma unroll
        for (int mh = 0; mh < 2; ++mh)
#pragma unroll
        for (int nh = 0; nh < 2; ++nh)
#pragma unroll
        for (int m = 0; m < MF2; ++m)
#pragma unroll
        for (int n = 0; n < 2; ++n) {
            const int c = gc0 + nh * 32 + n * 16;
            const float bv = bias[c];
#pragma unroll
            for (int j = 0; j < 4; ++j) {
                const int r = gr0 + (mh * MF2 + m) * 16 + j;
                float v = acc[mh][nh][m][n][j] + bv;
                C[(size_t)r * N + c] = v / (1.f + __expf(-v));
            }
        }
    }
#undef LOADA
#undef LOADB
#undef MMAQ
}

__global__ void cast8_kernel(const float* __restrict__ in, bf16_t* __restrict__ out, int n8) {
    const int i = blockIdx.x * blockDim.x + threadIdx.x;
    if (i >= n8) return;
    const float4* p = (const float4*)in + (size_t)i * 2;
    float4 a = p[0], b = p[1];
    bf16x8 v;
    v[0] = (bf16_t)a.x; v[1] = (bf16_t)a.y; v[2] = (bf16_t)a.z; v[3] = (bf16_t)a.w;
    v[4] = (bf16_t)b.x; v[5] = (bf16_t)b.y; v[6] = (bf16_t)b.z; v[7] = (bf16_t)b.w;
    *(bf16x8*)(out + (size_t)i * 8) = v;
}

// out[c*R + r] = in[r*C + c]   (in: R x C, out: C x R), cast to bf16
__global__ void transpose_cast_kernel(const float* __restrict__ in, bf16_t* __restrict__ out,
                                      int R, int C) {
    const int idx = blockIdx.x * blockDim.x + threadIdx.x;
    if (idx >= R * C) return;
    const int c = idx / R;
    const int r = idx - c * R;
    out[idx] = (bf16_t)in[(size_t)r * C + c];
}

// u[t] = sum_i v[i] * W[i][t]
__global__ void vecmat_kernel(const float* __restrict__ v, const float* __restrict__ W,
                              float* __restrict__ out) {
    const int t = blockIdx.x * blockDim.x + threadIdx.x;
    if (t >= 512) return;
    float s = 0.f;
    for (int i = 0; i < 512; ++i) s += v[i] * W[i * 512 + t];
    out[t] = s;
}

// per node: s = g.W3 ; chi_bo = chi*s ; A3[n, l*512+f] = c_l * g[f]^2
__global__ __launch_bounds__(256)
void mid_kernel(const bf16_t* __restrict__ G, const float* __restrict__ chi,
                const float* __restrict__ W3, float* __restrict__ chbo,
                bf16_t* __restrict__ A3)
{
    const int node = blockIdx.x * 4 + (threadIdx.x >> 6);
    const int lane = threadIdx.x & 63;

    const bf16x8 gv = *(const bf16x8*)(G + (size_t)node * 512 + lane * 8);
    float g[8];
#pragma unroll
    for (int j = 0; j < 8; ++j) g[j] = (float)gv[j];

    float s = 0.f;
    const float* w = W3 + lane * 8;
#pragma unroll
    for (int j = 0; j < 8; ++j) s += g[j] * w[j];
#pragma unroll
    for (int off = 32; off > 0; off >>= 1) s += __shfl_xor(s, off, 64);

    const float* ch = chi + (size_t)node * 15;
    float c0 = 0.f, c1 = 0.f, c2 = 0.f;
#pragma unroll
    for (int m = 0; m < 3; ++m)  c0 += ch[m] * ch[m];
#pragma unroll
    for (int m = 3; m < 8; ++m)  c1 += ch[m] * ch[m];
#pragma unroll
    for (int m = 8; m < 15; ++m) c2 += ch[m] * ch[m];

    if (lane < 15) chbo[(size_t)node * 15 + lane] = ch[lane] * s;

    const float cl[3] = {c0, c1, c2};
    bf16_t* arow = A3 + (size_t)node * 1536 + lane * 8;
#pragma unroll
    for (int l = 0; l < 3; ++l) {
        bf16x8 o;
#pragma unroll
        for (int j = 0; j < 8; ++j) o[j] = (bf16_t)(cl[l] * g[j] * g[j]);
        *(bf16x8*)(arow + l * 512) = o;
    }
}

extern "C" void kernel_launch(void* const* d_in, const int* in_sizes, int n_in,
                              void* d_out, int out_size, void* d_ws, size_t ws_size,
                              hipStream_t stream)
{
    const float* x   = (const float*)d_in[0];
    const float* chi = (const float*)d_in[1];
    // d_in[2] = z_one_hot : unused by the reference computation
    const float* W1  = (const float*)d_in[3];
    const float* b1  = (const float*)d_in[4];
    const float* W2  = (const float*)d_in[5];
    const float* W3  = (const float*)d_in[6];
    const float* W4  = (const float*)d_in[7];
    const float* b4  = (const float*)d_in[8];

    char* ws = (char*)d_ws;
    bf16_t* W1b = (bf16_t*)(ws + 0);
    bf16_t* W2t = (bf16_t*)(ws + 524288);
    bf16_t* W4t = (bf16_t*)(ws + 1048576);
    bf16_t* Wct = (bf16_t*)(ws + 2621440);
    float*  bc  = (float*) (ws + 3145728);
    float*  u   = (float*) (ws + 3147776);
    bf16_t* Xb  = (bf16_t*)(ws + 3149824);
    bf16_t* A3  = (bf16_t*)(ws + 3149824);   // overlaps Xb (dead by then)

    float*  xbo  = (float*)d_out;                                // 24576*512 f32
    float*  chbo = (float*)d_out + (size_t)24576 * 512;          // 24576*15 f32
    bf16_t* Gb   = (bf16_t*)d_out;   // bf16 scratch inside chunk0 (dead before final GEMM)

    // prep: casts / transposes / fused bias  bc = (b1 @ W1) @ W2
    cast8_kernel<<<6144, 256, 0, stream>>>(x, Xb, 1572864);
    cast8_kernel<<<128, 256, 0, stream>>>(W1, W1b, 32768);
    transpose_cast_kernel<<<1024, 256, 0, stream>>>(W2, W2t, 512, 512);
    transpose_cast_kernel<<<3072, 256, 0, stream>>>(W4, W4t, 1536, 512);
    vecmat_kernel<<<2, 256, 0, stream>>>(b1, W1, u);
    vecmat_kernel<<<2, 256, 0, stream>>>(u, W2, bc);

    // Wct = (W1@W2)^T = W2^T @ W1^T :  C[j][i] = sum_t W2t[j][t] * W1[i][t]
    gemm_bt_kernel<8><<<dim3(2, 2), 512, 0, stream>>>(W2t, W1b, nullptr, Wct, 512, 512, 0);

    // G = x @ (W1@W2) + bc : C[n][j] = sum_k Xb[n][k] * Wct[j][k] + bc[j]  -> bf16
    gemm_bt_kernel<6><<<dim3(128, 2), 512, 0, stream>>>(Xb, Wct, bc, Gb, 512, 512, 0);

    // s, chi_bo, A3
    mid_kernel<<<6144, 256, 0, stream>>>(Gb, chi, W3, chbo, A3);

    // x_bo = silu(A3 @ W4 + b4) : C[n][j] = sum_k A3[n][k] * W4t[j][k]
    gemm_bt_kernel<6><<<dim3(128, 2), 512, 0, stream>>>(A3, W4t, b4, xbo, 512, 1536, 1);
}